// Round 4
// baseline (732.880 us; speedup 1.0000x reference)
//
#include <hip/hip_runtime.h>
#include <stdint.h>

#define NN 100000
#define NE 1600000
#define NG 1000
#define FIN 128
#define DIM 32
#define NC 10

#define NBKT 512          // dst super-buckets
#define NPB 196           // nodes per bucket (512*196 >= NN)
#define BCAP 4096         // edges per bucket (mean 3136)
#define RND 2048          // edges per binning block
#define CURS 16           // cursor stride in ints (one per 64-B line)
#define NT 4              // src tiles
#define TLEN 25000        // nodes per src tile (bf16 window = 1.6 MB < 4 MiB XCD L2)
#define NKEY (NPB * NT)   // 784 sort keys per bucket

typedef unsigned int u32;

__device__ __forceinline__ ushort f2bf(float f) {
    u32 b = __float_as_uint(f);
    return (ushort)((b + 0x7FFFu + ((b >> 16) & 1u)) >> 16);   // RNE
}
__device__ __forceinline__ float bf2f(ushort u) {
    return __uint_as_float(((u32)u) << 16);
}

// ---------------- zero ----------------
__global__ void k_zero(u32* __restrict__ p, int n) {
    int i = blockIdx.x * blockDim.x + threadIdx.x;
    if (i < n) p[i] = 0u;
}

// ---------------- binning: edges -> 512 dst-super-buckets, LDS write-combined ----------------
__global__ __launch_bounds__(256) void k_bin(const int* __restrict__ ei,
        const float* __restrict__ ew, int* __restrict__ cursor,
        uint2* __restrict__ ebuf) {
    __shared__ uint2  ent[RND];      // 16 KB
    __shared__ ushort bk16[RND];     //  4 KB
    __shared__ int cnt[NBKT];
    __shared__ int sA[NBKT];
    __shared__ int sB[NBKT];
    __shared__ int gbase[NBKT];
    int tid = threadIdx.x;
    int e0 = blockIdx.x * RND;
    int n  = min(RND, NE - e0);
    if (n <= 0) return;

    for (int i = tid; i < NBKT; i += 256) cnt[i] = 0;
    __syncthreads();

    u32 pk[8], wv[8], bp[8];
    #pragma unroll
    for (int q = 0; q < 8; ++q) {
        int i = tid + q * 256;
        pk[q] = 0; wv[q] = 0; bp[q] = 0;
        if (i < n) {
            int s = ei[e0 + i];
            int d = ei[NE + e0 + i];
            float w = ew[e0 + i];
            int b = d / NPB;
            int loc = d - b * NPB;
            int p = atomicAdd(&cnt[b], 1);
            pk[q] = (u32)s | ((u32)loc << 17);
            wv[q] = __float_as_uint(w);
            bp[q] = (u32)p | ((u32)b << 16);
        }
    }
    __syncthreads();

    for (int i = tid; i < NBKT; i += 256) sA[i] = cnt[i];
    __syncthreads();
    int* ssrc = sA; int* sdst = sB;
    for (int dd = 1; dd < NBKT; dd <<= 1) {
        for (int i = tid; i < NBKT; i += 256)
            sdst[i] = ssrc[i] + (i >= dd ? ssrc[i - dd] : 0);
        __syncthreads();
        int* t = ssrc; ssrc = sdst; sdst = t;
    }
    for (int i = tid; i < NBKT; i += 256) {
        int excl = ssrc[i] - cnt[i];
        sdst[i] = excl;
        if (cnt[i] > 0) gbase[i] = atomicAdd(&cursor[i * CURS], cnt[i]);
    }
    __syncthreads();
    int* basep = sdst;

    #pragma unroll
    for (int q = 0; q < 8; ++q) {
        int i = tid + q * 256;
        if (i < n) {
            int b = (int)(bp[q] >> 16);
            int p = (int)(bp[q] & 0xFFFFu);
            int pos = basep[b] + p;
            ent[pos]  = make_uint2(pk[q], wv[q]);
            bk16[pos] = (ushort)b;
        }
    }
    __syncthreads();

    for (int i = tid; i < n; i += 256) {
        int b = (int)bk16[i];
        int dsti = gbase[b] + (i - basep[b]);
        if (dsti < BCAP) ebuf[(size_t)b * BCAP + dsti] = ent[i];
    }
}

// ---------------- CSR: sort each bucket by (loc, src-tile); emit packed (off,deg) per (node,tile) ----------------
__global__ __launch_bounds__(256) void k_csr(uint2* __restrict__ ebuf,
        const int* __restrict__ cursor, u32* __restrict__ od) {
    __shared__ uint2 ent[BCAP];      // 32 KB
    __shared__ int hist[NKEY];       // 784 bins
    __shared__ int sA[NKEY];
    __shared__ int sB[NKEY];
    __shared__ int base[NKEY];
    int tid = threadIdx.x;
    int bkt = blockIdx.x;
    int cnt = min(cursor[bkt * CURS], BCAP);
    for (int i = tid; i < NKEY; i += 256) hist[i] = 0;
    __syncthreads();
    uint2* gb = ebuf + (size_t)bkt * BCAP;
    uint2 my[16]; int mp[16]; int mk[16];
    #pragma unroll
    for (int q = 0; q < 16; ++q) {
        int i = tid + q * 256;
        mp[q] = -1;
        if (i < cnt) {
            my[q] = gb[i];
            int loc = (int)(my[q].x >> 17);
            int s   = (int)(my[q].x & 0x1FFFFu);
            int t   = s / TLEN;
            mk[q] = loc * NT + t;
            mp[q] = atomicAdd(&hist[mk[q]], 1);
        }
    }
    __syncthreads();
    for (int i = tid; i < NKEY; i += 256) sA[i] = hist[i];
    __syncthreads();
    int* ssrc = sA; int* sdst = sB;
    for (int dd = 1; dd < NKEY; dd <<= 1) {
        for (int i = tid; i < NKEY; i += 256)
            sdst[i] = ssrc[i] + (i >= dd ? ssrc[i - dd] : 0);
        __syncthreads();
        int* t = ssrc; ssrc = sdst; sdst = t;
    }
    for (int i = tid; i < NKEY; i += 256) base[i] = ssrc[i] - hist[i];
    __syncthreads();
    #pragma unroll
    for (int q = 0; q < 16; ++q) {
        if (mp[q] >= 0) ent[base[mk[q]] + mp[q]] = my[q];
    }
    __syncthreads();
    for (int i = tid; i < cnt; i += 256) gb[i] = ent[i];
    for (int i = tid; i < NPB; i += 256) {
        int node = bkt * NPB + i;
        if (node < NN) {
            #pragma unroll
            for (int t = 0; t < NT; ++t) {
                int key = i * NT + t;
                u32 off = (u32)(bkt * BCAP + base[key]);
                u32 dg  = (u32)min(hist[key], 2047);
                od[(size_t)t * NN + node] = (off << 11) | dg;
            }
        }
    }
}

// ---------------- layer-1 matmul: y(bf16) = x@Wrel ; agg = x@Wroot + brel ----------------
__global__ __launch_bounds__(256) void k_mm1(const float* __restrict__ x,
        const float* __restrict__ Wrel, const float* __restrict__ brel,
        const float* __restrict__ Wroot,
        ushort* __restrict__ ybf, float* __restrict__ aggi) {
    __shared__ float wr[FIN * DIM];
    __shared__ float wo[FIN * DIM];
    __shared__ float xs[128 * 36];
    int tid = threadIdx.x;
    for (int i = tid; i < FIN * DIM / 4; i += 256) {
        ((float4*)wr)[i] = ((const float4*)Wrel)[i];
        ((float4*)wo)[i] = ((const float4*)Wroot)[i];
    }
    int l  = tid & 7;
    int ng = tid >> 3;
    int base = blockIdx.x * 128;
    float4 b4 = ((const float4*)brel)[l];
    float4 aR[4], aO[4];
    #pragma unroll
    for (int r = 0; r < 4; ++r) {
        aR[r] = make_float4(0.f, 0.f, 0.f, 0.f);
        aO[r] = b4;
    }
    for (int kc = 0; kc < 4; ++kc) {
        __syncthreads();
        for (int i = tid; i < 1024; i += 256) {
            int r = i >> 3, c = i & 7;
            int node = base + r;
            float4 v = make_float4(0.f, 0.f, 0.f, 0.f);
            if (node < NN) v = ((const float4*)x)[(size_t)node * 32 + kc * 8 + c];
            ((float4*)xs)[r * 9 + c] = v;
        }
        __syncthreads();
        #pragma unroll 4
        for (int kk = 0; kk < 32; ++kk) {
            int k = kc * 32 + kk;
            float4 w1 = ((float4*)wr)[k * 8 + l];
            float4 w2 = ((float4*)wo)[k * 8 + l];
            #pragma unroll
            for (int r = 0; r < 4; ++r) {
                float hv = xs[(ng + 32 * r) * 36 + kk];
                aR[r].x += hv * w1.x; aR[r].y += hv * w1.y;
                aR[r].z += hv * w1.z; aR[r].w += hv * w1.w;
                aO[r].x += hv * w2.x; aO[r].y += hv * w2.y;
                aO[r].z += hv * w2.z; aO[r].w += hv * w2.w;
            }
        }
    }
    #pragma unroll
    for (int r = 0; r < 4; ++r) {
        int node = base + ng + 32 * r;
        if (node < NN) {
            ushort4 yo;
            yo.x = f2bf(aR[r].x); yo.y = f2bf(aR[r].y);
            yo.z = f2bf(aR[r].z); yo.w = f2bf(aR[r].w);
            ((ushort4*)ybf)[(size_t)node * 8 + l] = yo;
            ((float4*)aggi)[(size_t)node * 8 + l] = aO[r];
        }
    }
}

// ---------------- layers 2-5 matmul: in = cur + P0+P1+P2 ; h=relu(in); y=h@Wrel; agg=h@Wroot+brel ----------------
__global__ __launch_bounds__(256) void k_mm_small(const float* __restrict__ cur,
        const float* __restrict__ P,
        const float* __restrict__ Wrel, const float* __restrict__ brel,
        const float* __restrict__ Wroot,
        ushort* __restrict__ ybf, float* __restrict__ aggi) {
    __shared__ float wr[DIM * DIM];
    __shared__ float wo[DIM * DIM];
    __shared__ float hs[128 * 36];
    int tid = threadIdx.x;
    for (int i = tid; i < DIM * DIM / 4; i += 256) {
        ((float4*)wr)[i] = ((const float4*)Wrel)[i];
        ((float4*)wo)[i] = ((const float4*)Wroot)[i];
    }
    int l  = tid & 7;
    int ng = tid >> 3;
    int base = blockIdx.x * 128;
    float4 b4 = ((const float4*)brel)[l];
    const float4* P0 = (const float4*)P;
    const float4* P1 = (const float4*)(P + (size_t)NN * DIM);
    const float4* P2 = (const float4*)(P + (size_t)2 * NN * DIM);
    __syncthreads();
    for (int i = tid; i < 1024; i += 256) {
        int r = i >> 3, c = i & 7;
        int node = base + r;
        float4 v = make_float4(0.f, 0.f, 0.f, 0.f);
        if (node < NN) {
            size_t idx = (size_t)node * 8 + c;
            float4 a = ((const float4*)cur)[idx];
            float4 p0 = P0[idx], p1 = P1[idx], p2 = P2[idx];
            v.x = fmaxf(a.x + p0.x + p1.x + p2.x, 0.f);
            v.y = fmaxf(a.y + p0.y + p1.y + p2.y, 0.f);
            v.z = fmaxf(a.z + p0.z + p1.z + p2.z, 0.f);
            v.w = fmaxf(a.w + p0.w + p1.w + p2.w, 0.f);
        }
        ((float4*)hs)[r * 9 + c] = v;
    }
    __syncthreads();
    float4 aR[4], aO[4];
    #pragma unroll
    for (int r = 0; r < 4; ++r) {
        aR[r] = make_float4(0.f, 0.f, 0.f, 0.f);
        aO[r] = b4;
    }
    #pragma unroll 4
    for (int k = 0; k < DIM; ++k) {
        float4 w1 = ((float4*)wr)[k * 8 + l];
        float4 w2 = ((float4*)wo)[k * 8 + l];
        #pragma unroll
        for (int r = 0; r < 4; ++r) {
            float hv = hs[(ng + 32 * r) * 36 + k];
            aR[r].x += hv * w1.x; aR[r].y += hv * w1.y;
            aR[r].z += hv * w1.z; aR[r].w += hv * w1.w;
            aO[r].x += hv * w2.x; aO[r].y += hv * w2.y;
            aO[r].z += hv * w2.z; aO[r].w += hv * w2.w;
        }
    }
    #pragma unroll
    for (int r = 0; r < 4; ++r) {
        int node = base + ng + 32 * r;
        if (node < NN) {
            ushort4 yo;
            yo.x = f2bf(aR[r].x); yo.y = f2bf(aR[r].y);
            yo.z = f2bf(aR[r].z); yo.w = f2bf(aR[r].w);
            ((ushort4*)ybf)[(size_t)node * 8 + l] = yo;
            ((float4*)aggi)[(size_t)node * 8 + l] = aO[r];
        }
    }
}

// ---------------- gather, src-tiled: tile-major grid; t0 -> agg +=, t1..3 -> partial buffers ----------------
__global__ __launch_bounds__(256) void k_gather(const ushort* __restrict__ ybf,
        const uint2* __restrict__ ebuf, const u32* __restrict__ od,
        float* __restrict__ agg, float* __restrict__ P) {
    int tid = threadIdx.x;
    int f = tid & 31;
    int t   = blockIdx.x / 12500;         // tile-major dispatch: resident blocks share the y window
    int blk = blockIdx.x - t * 12500;
    int node = blk * 8 + (tid >> 5);
    if (node >= NN) return;
    u32 pk = od[(size_t)t * NN + node];
    int off = (int)(pk >> 11);
    int deg = (int)(pk & 2047u);
    float acc = 0.f;
    for (int b = 0; b < deg; b += 8) {
        #pragma unroll
        for (int jj = 0; jj < 8; ++jj) {
            int j = b + jj;
            uint2 e = ebuf[(size_t)off + j];            // pad keeps masked reads in-bounds
            bool ok = j < deg;
            u32 sidx = ok ? (e.x & 0x1FFFFu) : 0u;      // masked lanes pin to row 0 (L1 hit)
            float w  = ok ? __uint_as_float(e.y) : 0.f;
            acc += w * bf2f(ybf[(size_t)sidx * DIM + f]);
        }
    }
    size_t o = (size_t)node * DIM + f;
    if (t == 0) agg[o] += acc;
    else        P[(size_t)(t - 1) * NN * DIM + o] = acc;
}

// ---------------- pool: g[batch[n]] += relu(cur + P0+P1+P2); batch sorted ----------------
#define STRIP 32
__global__ __launch_bounds__(256) void k_pool(const float* __restrict__ cur,
        const float* __restrict__ P,
        const int* __restrict__ batch, float* __restrict__ g) {
    int tid = threadIdx.x;
    int lane = tid & 31;
    int grp = blockIdx.x * 8 + (tid >> 5);
    int start = grp * STRIP;
    if (start >= NN) return;
    int end = min(start + STRIP, NN);
    const float* P0 = P;
    const float* P1 = P + (size_t)NN * DIM;
    const float* P2 = P + (size_t)2 * NN * DIM;
    int curb = batch[start];
    float run = 0.f;
    for (int n = start; n < end; ++n) {
        int b = batch[n];
        if (b != curb) {
            atomicAdd(&g[(size_t)curb * DIM + lane], run);
            run = 0.f; curb = b;
        }
        size_t o = (size_t)n * DIM + lane;
        run += fmaxf(cur[o] + P0[o] + P1[o] + P2[o], 0.f);
    }
    atomicAdd(&g[(size_t)curb * DIM + lane], run);
}

// ---------------- head ----------------
__global__ __launch_bounds__(64) void k_head(const float* __restrict__ g,
        const float* __restrict__ W1, const float* __restrict__ b1,
        const float* __restrict__ W2, const float* __restrict__ b2,
        float* __restrict__ out) {
    __shared__ float gs[DIM];
    __shared__ float a1[DIM];
    __shared__ float lg[NC];
    int t = threadIdx.x;
    int gr = blockIdx.x;
    if (t < DIM) gs[t] = g[(size_t)gr * DIM + t];
    __syncthreads();
    if (t < DIM) {
        float a = b1[t];
        #pragma unroll
        for (int k = 0; k < DIM; ++k) a += gs[k] * W1[k * DIM + t];
        a1[t] = fmaxf(a, 0.f);
    }
    __syncthreads();
    if (t < NC) {
        float a = b2[t];
        #pragma unroll
        for (int k = 0; k < DIM; ++k) a += a1[k] * W2[k * NC + t];
        lg[t] = a;
    }
    __syncthreads();
    if (t == 0) {
        float m = lg[0];
        for (int c = 1; c < NC; ++c) m = fmaxf(m, lg[c]);
        float s = 0.f;
        for (int c = 0; c < NC; ++c) s += expf(lg[c] - m);
        float ls = m + logf(s);
        for (int c = 0; c < NC; ++c) out[(size_t)gr * NC + c] = lg[c] - ls;
    }
}

extern "C" void kernel_launch(void* const* d_in, const int* in_sizes, int n_in,
                              void* d_out, int out_size, void* d_ws, size_t ws_size,
                              hipStream_t stream) {
    const float* x     = (const float*)d_in[0];
    const int*   ei    = (const int*)d_in[1];
    const int*   batch = (const int*)d_in[2];
    const float* ew    = (const float*)d_in[3];
    const float* Wrel[5]  = {(const float*)d_in[4],  (const float*)d_in[7],  (const float*)d_in[10], (const float*)d_in[13], (const float*)d_in[16]};
    const float* brel[5]  = {(const float*)d_in[5],  (const float*)d_in[8],  (const float*)d_in[11], (const float*)d_in[14], (const float*)d_in[17]};
    const float* Wroot[5] = {(const float*)d_in[6],  (const float*)d_in[9],  (const float*)d_in[12], (const float*)d_in[15], (const float*)d_in[18]};
    const float* W1 = (const float*)d_in[19];
    const float* b1 = (const float*)d_in[20];
    const float* W2 = (const float*)d_in[21];
    const float* b2 = (const float*)d_in[22];
    float* out = (float*)d_out;

    char* ws = (char*)d_ws;
    const size_t off_cursor = 0;                                   // 512*16*4 = 32768
    const size_t off_g      = 32768;                               // 128000
    const size_t zero_end   = 160768;
    const size_t off_ebuf   = 160768;                              // (512*4096+64)*8 = 16,777,728
    const size_t off_od     = off_ebuf + ((size_t)NBKT * BCAP + 64) * 8;
    const size_t off_A      = off_od + (size_t)NT * NN * 4;        // od packed u32
    const size_t off_B      = off_A + (size_t)NN * DIM * 4;
    const size_t off_C      = off_B + (size_t)NN * DIM * 2;
    const size_t off_P      = off_C + (size_t)NN * DIM * 4;
    const size_t need       = off_P + (size_t)3 * NN * DIM * 4;    // ~89.0 MB
    if (ws_size < need) return;

    int*    cursor = (int*)(ws + off_cursor);
    float*  g      = (float*)(ws + off_g);
    uint2*  ebuf   = (uint2*)(ws + off_ebuf);
    u32*    od     = (u32*)(ws + off_od);
    float*  A      = (float*)(ws + off_A);
    ushort* B      = (ushort*)(ws + off_B);
    float*  C      = (float*)(ws + off_C);
    float*  P      = (float*)(ws + off_P);

    int zcount = (int)(zero_end / 4);
    k_zero<<<(zcount + 255) / 256, 256, 0, stream>>>((u32*)ws, zcount);

    const int nbin = (NE + RND - 1) / RND;             // 782
    k_bin<<<nbin, 256, 0, stream>>>(ei, ew, cursor, ebuf);
    k_csr<<<NBKT, 256, 0, stream>>>(ebuf, cursor, od);

    const int nmm = (NN + 127) / 128;                  // 782
    const int ngt = NT * 12500;                        // tile-major
    k_mm1<<<nmm, 256, 0, stream>>>(x, Wrel[0], brel[0], Wroot[0], B, A);
    k_gather<<<ngt, 256, 0, stream>>>(B, ebuf, od, A, P);

    float* cur = A; float* nxt = C;
    for (int L = 1; L < 5; ++L) {
        k_mm_small<<<nmm, 256, 0, stream>>>(cur, P, Wrel[L], brel[L], Wroot[L], B, nxt);
        k_gather<<<ngt, 256, 0, stream>>>(B, ebuf, od, nxt, P);
        float* tmp = cur; cur = nxt; nxt = tmp;
    }

    k_pool<<<391, 256, 0, stream>>>(cur, P, batch, g);
    k_head<<<NG, 64, 0, stream>>>(g, W1, b1, W2, b2, out);
}

// Round 5
// 500.818 us; speedup vs baseline: 1.4634x; 1.4634x over previous
//
#include <hip/hip_runtime.h>
#include <stdint.h>

#define NN 100000
#define NE 1600000
#define NG 1000
#define FIN 128
#define DIM 32
#define NC 10

#define NBKT 512          // super-buckets over dst nodes
#define NPB 196           // nodes per bucket (512*196 = 100352 >= NN)
#define BCAP 4096         // edges per bucket (mean 3136, ~17 sigma headroom)
#define RND 2048          // edges per binning block
#define CURS 16           // cursor stride in ints (one per 64-B line)

typedef unsigned int u32;

__device__ __forceinline__ ushort f2bf(float f) {
    u32 b = __float_as_uint(f);
    return (ushort)((b + 0x7FFFu + ((b >> 16) & 1u)) >> 16);   // RNE
}
__device__ __forceinline__ float bf2f(ushort u) {
    return __uint_as_float(((u32)u) << 16);
}

// ---------------- zero ----------------
__global__ void k_zero(u32* __restrict__ p, int n) {
    int i = blockIdx.x * blockDim.x + threadIdx.x;
    if (i < n) p[i] = 0u;
}

// ---------------- binning: edges -> 512 dst-super-buckets, LDS write-combined ----------------
__global__ __launch_bounds__(256) void k_bin(const int* __restrict__ ei,
        const float* __restrict__ ew, int* __restrict__ cursor,
        uint2* __restrict__ ebuf) {
    __shared__ uint2  ent[RND];      // 16 KB bucket-sorted entries
    __shared__ ushort bk16[RND];     //  4 KB bucket id per slot
    __shared__ int cnt[NBKT];
    __shared__ int sA[NBKT];
    __shared__ int sB[NBKT];
    __shared__ int gbase[NBKT];
    int tid = threadIdx.x;
    int e0 = blockIdx.x * RND;
    int n  = min(RND, NE - e0);
    if (n <= 0) return;

    for (int i = tid; i < NBKT; i += 256) cnt[i] = 0;
    __syncthreads();

    u32 pk[8], wv[8], bp[8];
    #pragma unroll
    for (int q = 0; q < 8; ++q) {
        int i = tid + q * 256;
        pk[q] = 0; wv[q] = 0; bp[q] = 0;
        if (i < n) {
            int s = ei[e0 + i];
            int d = ei[NE + e0 + i];
            float w = ew[e0 + i];
            int b = d / NPB;
            int loc = d - b * NPB;
            int p = atomicAdd(&cnt[b], 1);
            pk[q] = (u32)s | ((u32)loc << 17);
            wv[q] = __float_as_uint(w);
            bp[q] = (u32)p | ((u32)b << 16);
        }
    }
    __syncthreads();

    for (int i = tid; i < NBKT; i += 256) sA[i] = cnt[i];
    __syncthreads();
    int* ssrc = sA; int* sdst = sB;
    for (int dd = 1; dd < NBKT; dd <<= 1) {
        for (int i = tid; i < NBKT; i += 256)
            sdst[i] = ssrc[i] + (i >= dd ? ssrc[i - dd] : 0);
        __syncthreads();
        int* t = ssrc; ssrc = sdst; sdst = t;
    }
    for (int i = tid; i < NBKT; i += 256) {
        int excl = ssrc[i] - cnt[i];
        sdst[i] = excl;
        if (cnt[i] > 0) gbase[i] = atomicAdd(&cursor[i * CURS], cnt[i]);
    }
    __syncthreads();
    int* basep = sdst;

    #pragma unroll
    for (int q = 0; q < 8; ++q) {
        int i = tid + q * 256;
        if (i < n) {
            int b = (int)(bp[q] >> 16);
            int p = (int)(bp[q] & 0xFFFFu);
            int pos = basep[b] + p;
            ent[pos]  = make_uint2(pk[q], wv[q]);
            bk16[pos] = (ushort)b;
        }
    }
    __syncthreads();

    for (int i = tid; i < n; i += 256) {
        int b = (int)bk16[i];
        int dsti = gbase[b] + (i - basep[b]);
        if (dsti < BCAP) ebuf[(size_t)b * BCAP + dsti] = ent[i];
    }
}

// ---------------- CSR: counting-sort each bucket by local node, in place; emit (off,deg) ----------------
__global__ __launch_bounds__(256) void k_csr(uint2* __restrict__ ebuf,
        const int* __restrict__ cursor, uint2* __restrict__ od) {
    __shared__ uint2 ent[BCAP];      // 32 KB
    __shared__ int hist[NPB];
    __shared__ int sc[NPB];
    __shared__ int base[NPB];
    int tid = threadIdx.x;
    int bkt = blockIdx.x;
    int cnt = min(cursor[bkt * CURS], BCAP);
    for (int i = tid; i < NPB; i += 256) hist[i] = 0;
    __syncthreads();
    uint2* gb = ebuf + (size_t)bkt * BCAP;
    uint2 my[16]; int mp[16];
    #pragma unroll
    for (int q = 0; q < 16; ++q) {
        int i = tid + q * 256;
        mp[q] = -1;
        if (i < cnt) {
            my[q] = gb[i];
            int loc = (int)(my[q].x >> 17);
            mp[q] = atomicAdd(&hist[loc], 1);
        }
    }
    __syncthreads();
    for (int i = tid; i < NPB; i += 256) sc[i] = hist[i];
    __syncthreads();
    for (int dd = 1; dd < NPB; dd <<= 1) {
        int v = 0;
        if (tid < NPB) { v = sc[tid]; if (tid >= dd) v += sc[tid - dd]; }
        __syncthreads();
        if (tid < NPB) sc[tid] = v;
        __syncthreads();
    }
    for (int i = tid; i < NPB; i += 256) base[i] = sc[i] - hist[i];
    __syncthreads();
    #pragma unroll
    for (int q = 0; q < 16; ++q) {
        if (mp[q] >= 0) {
            int loc = (int)(my[q].x >> 17);
            ent[base[loc] + mp[q]] = my[q];
        }
    }
    __syncthreads();
    for (int i = tid; i < cnt; i += 256) gb[i] = ent[i];
    for (int i = tid; i < NPB; i += 256) {
        int node = bkt * NPB + i;
        if (node < NN)
            od[node] = make_uint2((u32)(bkt * BCAP + base[i]), (u32)hist[i]);
    }
}

// ---------------- layer-1 matmul: y(bf16) = x@Wrel ; agg = x@Wroot + brel ----------------
__global__ __launch_bounds__(256) void k_mm1(const float* __restrict__ x,
        const float* __restrict__ Wrel, const float* __restrict__ brel,
        const float* __restrict__ Wroot,
        ushort* __restrict__ ybf, float* __restrict__ aggi) {
    __shared__ float wr[FIN * DIM];
    __shared__ float wo[FIN * DIM];
    __shared__ float xs[128 * 36];
    int tid = threadIdx.x;
    for (int i = tid; i < FIN * DIM / 4; i += 256) {
        ((float4*)wr)[i] = ((const float4*)Wrel)[i];
        ((float4*)wo)[i] = ((const float4*)Wroot)[i];
    }
    int l  = tid & 7;
    int ng = tid >> 3;
    int base = blockIdx.x * 128;
    float4 b4 = ((const float4*)brel)[l];
    float4 aR[4], aO[4];
    #pragma unroll
    for (int r = 0; r < 4; ++r) {
        aR[r] = make_float4(0.f, 0.f, 0.f, 0.f);
        aO[r] = b4;
    }
    for (int kc = 0; kc < 4; ++kc) {
        __syncthreads();
        for (int i = tid; i < 1024; i += 256) {
            int r = i >> 3, c = i & 7;
            int node = base + r;
            float4 v = make_float4(0.f, 0.f, 0.f, 0.f);
            if (node < NN) v = ((const float4*)x)[(size_t)node * 32 + kc * 8 + c];
            ((float4*)xs)[r * 9 + c] = v;
        }
        __syncthreads();
        #pragma unroll 4
        for (int kk = 0; kk < 32; ++kk) {
            int k = kc * 32 + kk;
            float4 w1 = ((float4*)wr)[k * 8 + l];
            float4 w2 = ((float4*)wo)[k * 8 + l];
            #pragma unroll
            for (int r = 0; r < 4; ++r) {
                float hv = xs[(ng + 32 * r) * 36 + kk];
                aR[r].x += hv * w1.x; aR[r].y += hv * w1.y;
                aR[r].z += hv * w1.z; aR[r].w += hv * w1.w;
                aO[r].x += hv * w2.x; aO[r].y += hv * w2.y;
                aO[r].z += hv * w2.z; aO[r].w += hv * w2.w;
            }
        }
    }
    #pragma unroll
    for (int r = 0; r < 4; ++r) {
        int node = base + ng + 32 * r;
        if (node < NN) {
            ushort4 yo;
            yo.x = f2bf(aR[r].x); yo.y = f2bf(aR[r].y);
            yo.z = f2bf(aR[r].z); yo.w = f2bf(aR[r].w);
            ((ushort4*)ybf)[(size_t)node * 8 + l] = yo;
            ((float4*)aggi)[(size_t)node * 8 + l] = aO[r];
        }
    }
}

// ---------------- layers 2-5 matmul ----------------
__global__ __launch_bounds__(256) void k_mm_small(const float* __restrict__ in,
        const float* __restrict__ Wrel, const float* __restrict__ brel,
        const float* __restrict__ Wroot,
        ushort* __restrict__ ybf, float* __restrict__ aggi) {
    __shared__ float wr[DIM * DIM];
    __shared__ float wo[DIM * DIM];
    __shared__ float hs[128 * 36];
    int tid = threadIdx.x;
    for (int i = tid; i < DIM * DIM / 4; i += 256) {
        ((float4*)wr)[i] = ((const float4*)Wrel)[i];
        ((float4*)wo)[i] = ((const float4*)Wroot)[i];
    }
    int l  = tid & 7;
    int ng = tid >> 3;
    int base = blockIdx.x * 128;
    float4 b4 = ((const float4*)brel)[l];
    __syncthreads();
    for (int i = tid; i < 1024; i += 256) {
        int r = i >> 3, c = i & 7;
        int node = base + r;
        float4 v = make_float4(0.f, 0.f, 0.f, 0.f);
        if (node < NN) {
            v = ((const float4*)in)[(size_t)node * 8 + c];
            v.x = fmaxf(v.x, 0.f); v.y = fmaxf(v.y, 0.f);
            v.z = fmaxf(v.z, 0.f); v.w = fmaxf(v.w, 0.f);
        }
        ((float4*)hs)[r * 9 + c] = v;
    }
    __syncthreads();
    float4 aR[4], aO[4];
    #pragma unroll
    for (int r = 0; r < 4; ++r) {
        aR[r] = make_float4(0.f, 0.f, 0.f, 0.f);
        aO[r] = b4;
    }
    #pragma unroll 4
    for (int k = 0; k < DIM; ++k) {
        float4 w1 = ((float4*)wr)[k * 8 + l];
        float4 w2 = ((float4*)wo)[k * 8 + l];
        #pragma unroll
        for (int r = 0; r < 4; ++r) {
            float hv = hs[(ng + 32 * r) * 36 + k];
            aR[r].x += hv * w1.x; aR[r].y += hv * w1.y;
            aR[r].z += hv * w1.z; aR[r].w += hv * w1.w;
            aO[r].x += hv * w2.x; aO[r].y += hv * w2.y;
            aO[r].z += hv * w2.z; aO[r].w += hv * w2.w;
        }
    }
    #pragma unroll
    for (int r = 0; r < 4; ++r) {
        int node = base + ng + 32 * r;
        if (node < NN) {
            ushort4 yo;
            yo.x = f2bf(aR[r].x); yo.y = f2bf(aR[r].y);
            yo.z = f2bf(aR[r].z); yo.w = f2bf(aR[r].w);
            ((ushort4*)ybf)[(size_t)node * 8 + l] = yo;
            ((float4*)aggi)[(size_t)node * 8 + l] = aO[r];
        }
    }
}

// ---------------- gather: agg[n] += sum_j w_j * y[src_j] (CSR, deep MLP, nt streams) ----------------
__global__ __launch_bounds__(256) void k_gather(const ushort* __restrict__ ybf,
        const uint2* __restrict__ ebuf, const uint2* __restrict__ od,
        float* __restrict__ agg) {
    int tid = threadIdx.x;
    int f = tid & 31;
    int node = blockIdx.x * 8 + (tid >> 5);
    if (node >= NN) return;
    uint2 o = od[node];
    int off = (int)o.x;
    int deg = (int)o.y;
    const unsigned long long* eb64 = (const unsigned long long*)ebuf;
    float acc = 0.f;
    for (int b = 0; b < deg; b += 16) {
        // stage 16 entries (2 cache lines, nontemporal: don't evict hot y lines)
        unsigned long long e[16];
        #pragma unroll
        for (int jj = 0; jj < 16; ++jj)
            e[jj] = __builtin_nontemporal_load(eb64 + (size_t)off + b + jj);
        // issue 16 independent random y loads
        float yv[16];
        #pragma unroll
        for (int jj = 0; jj < 16; ++jj) {
            u32 sidx = (b + jj < deg) ? ((u32)e[jj] & 0x1FFFFu) : 0u;
            yv[jj] = bf2f(ybf[(size_t)sidx * DIM + f]);
        }
        #pragma unroll
        for (int jj = 0; jj < 16; ++jj) {
            float w = (b + jj < deg) ? __uint_as_float((u32)(e[jj] >> 32)) : 0.f;
            acc += w * yv[jj];
        }
    }
    size_t oo = (size_t)node * DIM + f;
    float prev = __builtin_nontemporal_load(&agg[oo]);
    __builtin_nontemporal_store(prev + acc, &agg[oo]);
}

// ---------------- pool: g[batch[n]] += relu(h[n]); batch sorted ----------------
#define STRIP 32
__global__ __launch_bounds__(256) void k_pool(const float* __restrict__ h,
        const int* __restrict__ batch, float* __restrict__ g) {
    int tid = threadIdx.x;
    int lane = tid & 31;
    int grp = blockIdx.x * 8 + (tid >> 5);
    int start = grp * STRIP;
    if (start >= NN) return;
    int end = min(start + STRIP, NN);
    int curb = batch[start];
    float run = 0.f;
    for (int n = start; n < end; ++n) {
        int b = batch[n];
        if (b != curb) {
            atomicAdd(&g[(size_t)curb * DIM + lane], run);
            run = 0.f; curb = b;
        }
        run += fmaxf(h[(size_t)n * DIM + lane], 0.f);
    }
    atomicAdd(&g[(size_t)curb * DIM + lane], run);
}

// ---------------- head ----------------
__global__ __launch_bounds__(64) void k_head(const float* __restrict__ g,
        const float* __restrict__ W1, const float* __restrict__ b1,
        const float* __restrict__ W2, const float* __restrict__ b2,
        float* __restrict__ out) {
    __shared__ float gs[DIM];
    __shared__ float a1[DIM];
    __shared__ float lg[NC];
    int t = threadIdx.x;
    int gr = blockIdx.x;
    if (t < DIM) gs[t] = g[(size_t)gr * DIM + t];
    __syncthreads();
    if (t < DIM) {
        float a = b1[t];
        #pragma unroll
        for (int k = 0; k < DIM; ++k) a += gs[k] * W1[k * DIM + t];
        a1[t] = fmaxf(a, 0.f);
    }
    __syncthreads();
    if (t < NC) {
        float a = b2[t];
        #pragma unroll
        for (int k = 0; k < DIM; ++k) a += a1[k] * W2[k * NC + t];
        lg[t] = a;
    }
    __syncthreads();
    if (t == 0) {
        float m = lg[0];
        for (int c = 1; c < NC; ++c) m = fmaxf(m, lg[c]);
        float s = 0.f;
        for (int c = 0; c < NC; ++c) s += expf(lg[c] - m);
        float ls = m + logf(s);
        for (int c = 0; c < NC; ++c) out[(size_t)gr * NC + c] = lg[c] - ls;
    }
}

extern "C" void kernel_launch(void* const* d_in, const int* in_sizes, int n_in,
                              void* d_out, int out_size, void* d_ws, size_t ws_size,
                              hipStream_t stream) {
    const float* x     = (const float*)d_in[0];
    const int*   ei    = (const int*)d_in[1];
    const int*   batch = (const int*)d_in[2];
    const float* ew    = (const float*)d_in[3];
    const float* Wrel[5]  = {(const float*)d_in[4],  (const float*)d_in[7],  (const float*)d_in[10], (const float*)d_in[13], (const float*)d_in[16]};
    const float* brel[5]  = {(const float*)d_in[5],  (const float*)d_in[8],  (const float*)d_in[11], (const float*)d_in[14], (const float*)d_in[17]};
    const float* Wroot[5] = {(const float*)d_in[6],  (const float*)d_in[9],  (const float*)d_in[12], (const float*)d_in[15], (const float*)d_in[18]};
    const float* W1 = (const float*)d_in[19];
    const float* b1 = (const float*)d_in[20];
    const float* W2 = (const float*)d_in[21];
    const float* b2 = (const float*)d_in[22];
    float* out = (float*)d_out;

    char* ws = (char*)d_ws;
    const size_t off_cursor = 0;                                   // 512*16*4 = 32768
    const size_t off_g      = 32768;                               // 128000
    const size_t zero_end   = 160768;
    const size_t off_ebuf   = 160768;                              // (512*4096+64)*8
    const size_t off_od     = off_ebuf + ((size_t)NBKT * BCAP + 64) * 8;
    const size_t off_A      = off_od + (size_t)NN * 8;
    const size_t off_B      = off_A + (size_t)NN * DIM * 4;
    const size_t off_C      = off_B + (size_t)NN * DIM * 2;
    const size_t need       = off_C + (size_t)NN * DIM * 4;        // ~50 MB
    if (ws_size < need) return;

    int*    cursor = (int*)(ws + off_cursor);
    float*  g      = (float*)(ws + off_g);
    uint2*  ebuf   = (uint2*)(ws + off_ebuf);
    uint2*  od     = (uint2*)(ws + off_od);
    float*  A      = (float*)(ws + off_A);
    ushort* B      = (ushort*)(ws + off_B);
    float*  C      = (float*)(ws + off_C);

    int zcount = (int)(zero_end / 4);
    k_zero<<<(zcount + 255) / 256, 256, 0, stream>>>((u32*)ws, zcount);

    const int nbin = (NE + RND - 1) / RND;             // 782
    k_bin<<<nbin, 256, 0, stream>>>(ei, ew, cursor, ebuf);
    k_csr<<<NBKT, 256, 0, stream>>>(ebuf, cursor, od);

    const int nmm = (NN + 127) / 128;                  // 782
    const int ngt = (NN + 7) / 8;                      // 12500
    k_mm1<<<nmm, 256, 0, stream>>>(x, Wrel[0], brel[0], Wroot[0], B, A);
    k_gather<<<ngt, 256, 0, stream>>>(B, ebuf, od, A);

    float* cur = A; float* nxt = C;
    for (int L = 1; L < 5; ++L) {
        k_mm_small<<<nmm, 256, 0, stream>>>(cur, Wrel[L], brel[L], Wroot[L], B, nxt);
        k_gather<<<ngt, 256, 0, stream>>>(B, ebuf, od, nxt);
        float* tmp = cur; cur = nxt; nxt = tmp;
    }

    k_pool<<<391, 256, 0, stream>>>(cur, batch, g);
    k_head<<<NG, 64, 0, stream>>>(g, W1, b1, W2, b2, out);
}

// Round 6
// 484.470 us; speedup vs baseline: 1.5127x; 1.0337x over previous
//
#include <hip/hip_runtime.h>
#include <stdint.h>

#define NN 100000
#define NE 1600000
#define NG 1000
#define FIN 128
#define DIM 32
#define NC 10

#define NBKT 512          // super-buckets over dst nodes
#define NPB 196           // nodes per bucket (512*196 = 100352 >= NN)
#define BCAP 4096         // edges per bucket (mean 3136, ~17 sigma headroom)
#define RND 2048          // edges per binning block
#define CURS 16           // cursor stride in ints (one per 64-B line)

typedef unsigned int u32;
typedef __attribute__((ext_vector_type(8))) short short8;
typedef __attribute__((ext_vector_type(4))) float floatx4;

__device__ __forceinline__ ushort f2bf(float f) {
    u32 b = __float_as_uint(f);
    return (ushort)((b + 0x7FFFu + ((b >> 16) & 1u)) >> 16);   // RNE
}
__device__ __forceinline__ float bf2f(ushort u) {
    return __uint_as_float(((u32)u) << 16);
}

// ---------------- zero ----------------
__global__ void k_zero(u32* __restrict__ p, int n) {
    int i = blockIdx.x * blockDim.x + threadIdx.x;
    if (i < n) p[i] = 0u;
}

// ---------------- binning: edges -> 512 dst-super-buckets, LDS write-combined ----------------
__global__ __launch_bounds__(256) void k_bin(const int* __restrict__ ei,
        const float* __restrict__ ew, int* __restrict__ cursor,
        uint2* __restrict__ ebuf) {
    __shared__ uint2  ent[RND];
    __shared__ ushort bk16[RND];
    __shared__ int cnt[NBKT];
    __shared__ int sA[NBKT];
    __shared__ int sB[NBKT];
    __shared__ int gbase[NBKT];
    int tid = threadIdx.x;
    int e0 = blockIdx.x * RND;
    int n  = min(RND, NE - e0);
    if (n <= 0) return;

    for (int i = tid; i < NBKT; i += 256) cnt[i] = 0;
    __syncthreads();

    u32 pk[8], wv[8], bp[8];
    #pragma unroll
    for (int q = 0; q < 8; ++q) {
        int i = tid + q * 256;
        pk[q] = 0; wv[q] = 0; bp[q] = 0;
        if (i < n) {
            int s = ei[e0 + i];
            int d = ei[NE + e0 + i];
            float w = ew[e0 + i];
            int b = d / NPB;
            int loc = d - b * NPB;
            int p = atomicAdd(&cnt[b], 1);
            pk[q] = (u32)s | ((u32)loc << 17);
            wv[q] = __float_as_uint(w);
            bp[q] = (u32)p | ((u32)b << 16);
        }
    }
    __syncthreads();

    for (int i = tid; i < NBKT; i += 256) sA[i] = cnt[i];
    __syncthreads();
    int* ssrc = sA; int* sdst = sB;
    for (int dd = 1; dd < NBKT; dd <<= 1) {
        for (int i = tid; i < NBKT; i += 256)
            sdst[i] = ssrc[i] + (i >= dd ? ssrc[i - dd] : 0);
        __syncthreads();
        int* t = ssrc; ssrc = sdst; sdst = t;
    }
    for (int i = tid; i < NBKT; i += 256) {
        int excl = ssrc[i] - cnt[i];
        sdst[i] = excl;
        if (cnt[i] > 0) gbase[i] = atomicAdd(&cursor[i * CURS], cnt[i]);
    }
    __syncthreads();
    int* basep = sdst;

    #pragma unroll
    for (int q = 0; q < 8; ++q) {
        int i = tid + q * 256;
        if (i < n) {
            int b = (int)(bp[q] >> 16);
            int p = (int)(bp[q] & 0xFFFFu);
            int pos = basep[b] + p;
            ent[pos]  = make_uint2(pk[q], wv[q]);
            bk16[pos] = (ushort)b;
        }
    }
    __syncthreads();

    for (int i = tid; i < n; i += 256) {
        int b = (int)bk16[i];
        int dsti = gbase[b] + (i - basep[b]);
        if (dsti < BCAP) ebuf[(size_t)b * BCAP + dsti] = ent[i];
    }
}

// ---------------- CSR: counting-sort each bucket by local node, in place; emit (off,deg) ----------------
__global__ __launch_bounds__(256) void k_csr(uint2* __restrict__ ebuf,
        const int* __restrict__ cursor, uint2* __restrict__ od) {
    __shared__ uint2 ent[BCAP];      // 32 KB
    __shared__ int hist[NPB];
    __shared__ int sc[NPB];
    __shared__ int base[NPB];
    int tid = threadIdx.x;
    int bkt = blockIdx.x;
    int cnt = min(cursor[bkt * CURS], BCAP);
    for (int i = tid; i < NPB; i += 256) hist[i] = 0;
    __syncthreads();
    uint2* gb = ebuf + (size_t)bkt * BCAP;
    uint2 my[16]; int mp[16];
    #pragma unroll
    for (int q = 0; q < 16; ++q) {
        int i = tid + q * 256;
        mp[q] = -1;
        if (i < cnt) {
            my[q] = gb[i];
            int loc = (int)(my[q].x >> 17);
            mp[q] = atomicAdd(&hist[loc], 1);
        }
    }
    __syncthreads();
    for (int i = tid; i < NPB; i += 256) sc[i] = hist[i];
    __syncthreads();
    for (int dd = 1; dd < NPB; dd <<= 1) {
        int v = 0;
        if (tid < NPB) { v = sc[tid]; if (tid >= dd) v += sc[tid - dd]; }
        __syncthreads();
        if (tid < NPB) sc[tid] = v;
        __syncthreads();
    }
    for (int i = tid; i < NPB; i += 256) base[i] = sc[i] - hist[i];
    __syncthreads();
    #pragma unroll
    for (int q = 0; q < 16; ++q) {
        if (mp[q] >= 0) {
            int loc = (int)(my[q].x >> 17);
            ent[base[loc] + mp[q]] = my[q];
        }
    }
    __syncthreads();
    for (int i = tid; i < cnt; i += 256) gb[i] = ent[i];
    for (int i = tid; i < NPB; i += 256) {
        int node = bkt * NPB + i;
        if (node < NN)
            od[node] = make_uint2((u32)(bkt * BCAP + base[i]), (u32)hist[i]);
    }
}

// ---------------- layer-1 matmul via bf16 MFMA: y(bf16)=x@Wrel ; agg=x@Wroot+brel ----------------
// 64 nodes/block, 4 waves; wave = one 16-node M-tile, N=64 ([Wrel|Wroot]), K=128.
// Layouts (HW-verified, guide §3): A[m=lane&15][k=(lane>>4)*8+j]; B[n=lane&15][k=(lane>>4)*8+j];
// C/D col=lane&15, row=(lane>>4)*4+reg.
__global__ __launch_bounds__(256) void k_mm1(const float* __restrict__ x,
        const float* __restrict__ Wrel, const float* __restrict__ brel,
        const float* __restrict__ Wroot,
        ushort* __restrict__ ybf, float* __restrict__ aggi) {
    __shared__ ushort xs[64 * 136];      // 64 nodes x 128 k (bf16), pitch 136 (16B-aligned rows)
    int tid = threadIdx.x;
    int base = blockIdx.x * 64;
    // stage x -> bf16 LDS (coalesced: 32 float4 per row)
    for (int i = tid; i < 64 * 32; i += 256) {
        int r = i >> 5, c = i & 31;
        int node = base + r;
        float4 v = make_float4(0.f, 0.f, 0.f, 0.f);
        if (node < NN) v = ((const float4*)x)[(size_t)node * 32 + c];
        ushort4 u;
        u.x = f2bf(v.x); u.y = f2bf(v.y); u.z = f2bf(v.z); u.w = f2bf(v.w);
        *(ushort4*)&xs[r * 136 + c * 4] = u;
    }
    int lane = tid & 63;
    int w = tid >> 6;            // wave id = M-tile
    int m = lane & 15;
    int q = lane >> 4;           // quad
    // B fragments in registers: [ntile][kchunk]; ntile 0,1 = Wrel cols 0-15,16-31; 2,3 = Wroot
    short8 bfr[4][4];
    #pragma unroll
    for (int nt = 0; nt < 4; ++nt) {
        const float* W = (nt < 2) ? Wrel : Wroot;
        int ncol = (nt & 1) * 16 + m;
        #pragma unroll
        for (int kc = 0; kc < 4; ++kc) {
            short8 f;
            #pragma unroll
            for (int j = 0; j < 8; ++j) {
                int k = kc * 32 + q * 8 + j;
                f[j] = (short)f2bf(W[k * 32 + ncol]);
            }
            bfr[nt][kc] = f;
        }
    }
    __syncthreads();
    floatx4 acc[4] = {{0.f,0.f,0.f,0.f},{0.f,0.f,0.f,0.f},{0.f,0.f,0.f,0.f},{0.f,0.f,0.f,0.f}};
    #pragma unroll
    for (int kc = 0; kc < 4; ++kc) {
        short8 af = *(const short8*)&xs[(w * 16 + m) * 136 + kc * 32 + q * 8];
        #pragma unroll
        for (int nt = 0; nt < 4; ++nt)
            acc[nt] = __builtin_amdgcn_mfma_f32_16x16x32_bf16(af, bfr[nt][kc], acc[nt], 0, 0, 0);
    }
    float br0 = brel[m], br1 = brel[16 + m];
    #pragma unroll
    for (int reg = 0; reg < 4; ++reg) {
        int row = q * 4 + reg;
        int node = base + w * 16 + row;
        if (node < NN) {
            ybf[(size_t)node * 32 + m]       = f2bf(acc[0][reg]);
            ybf[(size_t)node * 32 + 16 + m]  = f2bf(acc[1][reg]);
            aggi[(size_t)node * 32 + m]      = acc[2][reg] + br0;
            aggi[(size_t)node * 32 + 16 + m] = acc[3][reg] + br1;
        }
    }
}

// ---------------- layers 2-5 matmul (fp32 vector; K=32 is small) ----------------
__global__ __launch_bounds__(256) void k_mm_small(const float* __restrict__ in,
        const float* __restrict__ Wrel, const float* __restrict__ brel,
        const float* __restrict__ Wroot,
        ushort* __restrict__ ybf, float* __restrict__ aggi) {
    __shared__ float wr[DIM * DIM];
    __shared__ float wo[DIM * DIM];
    __shared__ float hs[128 * 36];
    int tid = threadIdx.x;
    for (int i = tid; i < DIM * DIM / 4; i += 256) {
        ((float4*)wr)[i] = ((const float4*)Wrel)[i];
        ((float4*)wo)[i] = ((const float4*)Wroot)[i];
    }
    int l  = tid & 7;
    int ng = tid >> 3;
    int base = blockIdx.x * 128;
    float4 b4 = ((const float4*)brel)[l];
    __syncthreads();
    for (int i = tid; i < 1024; i += 256) {
        int r = i >> 3, c = i & 7;
        int node = base + r;
        float4 v = make_float4(0.f, 0.f, 0.f, 0.f);
        if (node < NN) {
            v = ((const float4*)in)[(size_t)node * 8 + c];
            v.x = fmaxf(v.x, 0.f); v.y = fmaxf(v.y, 0.f);
            v.z = fmaxf(v.z, 0.f); v.w = fmaxf(v.w, 0.f);
        }
        ((float4*)hs)[r * 9 + c] = v;
    }
    __syncthreads();
    float4 aR[4], aO[4];
    #pragma unroll
    for (int r = 0; r < 4; ++r) {
        aR[r] = make_float4(0.f, 0.f, 0.f, 0.f);
        aO[r] = b4;
    }
    #pragma unroll 4
    for (int k = 0; k < DIM; ++k) {
        float4 w1 = ((float4*)wr)[k * 8 + l];
        float4 w2 = ((float4*)wo)[k * 8 + l];
        #pragma unroll
        for (int r = 0; r < 4; ++r) {
            float hv = hs[(ng + 32 * r) * 36 + k];
            aR[r].x += hv * w1.x; aR[r].y += hv * w1.y;
            aR[r].z += hv * w1.z; aR[r].w += hv * w1.w;
            aO[r].x += hv * w2.x; aO[r].y += hv * w2.y;
            aO[r].z += hv * w2.z; aO[r].w += hv * w2.w;
        }
    }
    #pragma unroll
    for (int r = 0; r < 4; ++r) {
        int node = base + ng + 32 * r;
        if (node < NN) {
            ushort4 yo;
            yo.x = f2bf(aR[r].x); yo.y = f2bf(aR[r].y);
            yo.z = f2bf(aR[r].z); yo.w = f2bf(aR[r].w);
            ((ushort4*)ybf)[(size_t)node * 8 + l] = yo;
            ((float4*)aggi)[(size_t)node * 8 + l] = aO[r];
        }
    }
}

// ---------------- gather: agg[n] += sum_j w_j * y[src_j] (CSR, deep MLP, nt streams) ----------------
__global__ __launch_bounds__(256) void k_gather(const ushort* __restrict__ ybf,
        const uint2* __restrict__ ebuf, const uint2* __restrict__ od,
        float* __restrict__ agg) {
    int tid = threadIdx.x;
    int f = tid & 31;
    int node = blockIdx.x * 8 + (tid >> 5);
    if (node >= NN) return;
    uint2 o = od[node];
    int off = (int)o.x;
    int deg = (int)o.y;
    const unsigned long long* eb64 = (const unsigned long long*)ebuf;
    float acc = 0.f;
    for (int b = 0; b < deg; b += 16) {
        unsigned long long e[16];
        #pragma unroll
        for (int jj = 0; jj < 16; ++jj)
            e[jj] = __builtin_nontemporal_load(eb64 + (size_t)off + b + jj);
        float yv[16];
        #pragma unroll
        for (int jj = 0; jj < 16; ++jj) {
            u32 sidx = (b + jj < deg) ? ((u32)e[jj] & 0x1FFFFu) : 0u;
            yv[jj] = bf2f(ybf[(size_t)sidx * DIM + f]);
        }
        #pragma unroll
        for (int jj = 0; jj < 16; ++jj) {
            float w = (b + jj < deg) ? __uint_as_float((u32)(e[jj] >> 32)) : 0.f;
            acc += w * yv[jj];
        }
    }
    size_t oo = (size_t)node * DIM + f;
    float prev = __builtin_nontemporal_load(&agg[oo]);
    __builtin_nontemporal_store(prev + acc, &agg[oo]);
}

// ---------------- pool: g[batch[n]] += relu(h[n]); batch sorted ----------------
#define STRIP 32
__global__ __launch_bounds__(256) void k_pool(const float* __restrict__ h,
        const int* __restrict__ batch, float* __restrict__ g) {
    int tid = threadIdx.x;
    int lane = tid & 31;
    int grp = blockIdx.x * 8 + (tid >> 5);
    int start = grp * STRIP;
    if (start >= NN) return;
    int end = min(start + STRIP, NN);
    int curb = batch[start];
    float run = 0.f;
    for (int n = start; n < end; ++n) {
        int b = batch[n];
        if (b != curb) {
            atomicAdd(&g[(size_t)curb * DIM + lane], run);
            run = 0.f; curb = b;
        }
        run += fmaxf(h[(size_t)n * DIM + lane], 0.f);
    }
    atomicAdd(&g[(size_t)curb * DIM + lane], run);
}

// ---------------- head ----------------
__global__ __launch_bounds__(64) void k_head(const float* __restrict__ g,
        const float* __restrict__ W1, const float* __restrict__ b1,
        const float* __restrict__ W2, const float* __restrict__ b2,
        float* __restrict__ out) {
    __shared__ float gs[DIM];
    __shared__ float a1[DIM];
    __shared__ float lg[NC];
    int t = threadIdx.x;
    int gr = blockIdx.x;
    if (t < DIM) gs[t] = g[(size_t)gr * DIM + t];
    __syncthreads();
    if (t < DIM) {
        float a = b1[t];
        #pragma unroll
        for (int k = 0; k < DIM; ++k) a += gs[k] * W1[k * DIM + t];
        a1[t] = fmaxf(a, 0.f);
    }
    __syncthreads();
    if (t < NC) {
        float a = b2[t];
        #pragma unroll
        for (int k = 0; k < DIM; ++k) a += a1[k] * W2[k * NC + t];
        lg[t] = a;
    }
    __syncthreads();
    if (t == 0) {
        float m = lg[0];
        for (int c = 1; c < NC; ++c) m = fmaxf(m, lg[c]);
        float s = 0.f;
        for (int c = 0; c < NC; ++c) s += expf(lg[c] - m);
        float ls = m + logf(s);
        for (int c = 0; c < NC; ++c) out[(size_t)gr * NC + c] = lg[c] - ls;
    }
}

extern "C" void kernel_launch(void* const* d_in, const int* in_sizes, int n_in,
                              void* d_out, int out_size, void* d_ws, size_t ws_size,
                              hipStream_t stream) {
    const float* x     = (const float*)d_in[0];
    const int*   ei    = (const int*)d_in[1];
    const int*   batch = (const int*)d_in[2];
    const float* ew    = (const float*)d_in[3];
    const float* Wrel[5]  = {(const float*)d_in[4],  (const float*)d_in[7],  (const float*)d_in[10], (const float*)d_in[13], (const float*)d_in[16]};
    const float* brel[5]  = {(const float*)d_in[5],  (const float*)d_in[8],  (const float*)d_in[11], (const float*)d_in[14], (const float*)d_in[17]};
    const float* Wroot[5] = {(const float*)d_in[6],  (const float*)d_in[9],  (const float*)d_in[12], (const float*)d_in[15], (const float*)d_in[18]};
    const float* W1 = (const float*)d_in[19];
    const float* b1 = (const float*)d_in[20];
    const float* W2 = (const float*)d_in[21];
    const float* b2 = (const float*)d_in[22];
    float* out = (float*)d_out;

    char* ws = (char*)d_ws;
    const size_t off_cursor = 0;                                   // 512*16*4 = 32768
    const size_t off_g      = 32768;                               // 128000
    const size_t zero_end   = 160768;
    const size_t off_ebuf   = 160768;                              // (512*4096+64)*8
    const size_t off_od     = off_ebuf + ((size_t)NBKT * BCAP + 64) * 8;
    const size_t off_A      = off_od + (size_t)NN * 8;
    const size_t off_B      = off_A + (size_t)NN * DIM * 4;
    const size_t off_C      = off_B + (size_t)NN * DIM * 2;
    const size_t need       = off_C + (size_t)NN * DIM * 4;        // ~50 MB
    if (ws_size < need) return;

    int*    cursor = (int*)(ws + off_cursor);
    float*  g      = (float*)(ws + off_g);
    uint2*  ebuf   = (uint2*)(ws + off_ebuf);
    uint2*  od     = (uint2*)(ws + off_od);
    float*  A      = (float*)(ws + off_A);
    ushort* B      = (ushort*)(ws + off_B);
    float*  C      = (float*)(ws + off_C);

    int zcount = (int)(zero_end / 4);
    k_zero<<<(zcount + 255) / 256, 256, 0, stream>>>((u32*)ws, zcount);

    const int nbin = (NE + RND - 1) / RND;             // 782
    k_bin<<<nbin, 256, 0, stream>>>(ei, ew, cursor, ebuf);
    k_csr<<<NBKT, 256, 0, stream>>>(ebuf, cursor, od);

    const int nmm1 = (NN + 63) / 64;                   // 1563
    const int nmm  = (NN + 127) / 128;                 // 782
    const int ngt  = (NN + 7) / 8;                     // 12500
    k_mm1<<<nmm1, 256, 0, stream>>>(x, Wrel[0], brel[0], Wroot[0], B, A);
    k_gather<<<ngt, 256, 0, stream>>>(B, ebuf, od, A);

    float* cur = A; float* nxt = C;
    for (int L = 1; L < 5; ++L) {
        k_mm_small<<<nmm, 256, 0, stream>>>(cur, Wrel[L], brel[L], Wroot[L], B, nxt);
        k_gather<<<ngt, 256, 0, stream>>>(B, ebuf, od, nxt);
        float* tmp = cur; cur = nxt; nxt = tmp;
    }

    k_pool<<<391, 256, 0, stream>>>(cur, batch, g);
    k_head<<<NG, 64, 0, stream>>>(g, W1, b1, W2, b2, out);
}